// Round 1
// baseline (214.317 us; speedup 1.0000x reference)
//
#include <hip/hip_runtime.h>
#include <hip/hip_bf16.h>

// Problem constants (from reference)
#define BATCH_N   16384
#define FEAT      128      // MOVIE_FEAT == USER_FEAT
#define NNBR      50
#define NUM_MOVIES_N 100000

typedef short  short8  __attribute__((ext_vector_type(8)));
typedef float  floatx4 __attribute__((ext_vector_type(4)));
typedef unsigned int u32;

__device__ __forceinline__ __hip_bfloat16 f2bf(float x) { return __float2bfloat16(x); }
__device__ __forceinline__ float bfb2f(short s) {
  union { u32 u; float f; } c; c.u = ((u32)(unsigned short)s) << 16; return c.f;
}

// async global->LDS 16B DMA. LDS dst must be wave-uniform base + lane*16
// (m104), so the XOR swizzle is applied to the SOURCE index.
__device__ __forceinline__ void gld16(const __hip_bfloat16* g, __hip_bfloat16* l) {
  __builtin_amdgcn_global_load_lds(
      (const __attribute__((address_space(1))) u32*)g,
      (__attribute__((address_space(3))) u32*)l, 16, 0, 0);
}

__device__ __forceinline__ floatx4 mfma16(short8 a, short8 b, floatx4 c) {
  return __builtin_amdgcn_mfma_f32_16x16x32_bf16(a, b, c, 0, 0, 0);
}

// ---------------------------------------------------------------------------
// prep_all: fused (a) fp32 movie_table -> bf16 copy and (b) bf16 transposed
// weights Wt[n][k] + fused bias bu+bm. One launch instead of two.
// blocks [0,6250): conv;  [6250,6506): weight prep.
// ---------------------------------------------------------------------------
#define CONV_BLOCKS (NUM_MOVIES_N * FEAT / (256 * 8))   // 6250
__global__ __launch_bounds__(256) void prep_all(
    const float* __restrict__ t, __hip_bfloat16* __restrict__ tb,
    const float* __restrict__ Wu, const float* __restrict__ Wm,
    const float* __restrict__ W1, const float* __restrict__ W2,
    const float* __restrict__ bu, const float* __restrict__ bm,
    __hip_bfloat16* __restrict__ WcatT, __hip_bfloat16* __restrict__ WmT,
    __hip_bfloat16* __restrict__ W1T,  __hip_bfloat16* __restrict__ W2T,
    float* __restrict__ bc) {
  int bid = blockIdx.x;
  if (bid < CONV_BLOCKS) {
    size_t i = ((size_t)bid * 256 + threadIdx.x) * 8;
    float4 v0 = *(const float4*)(t + i);
    float4 v1 = *(const float4*)(t + i + 4);
    __hip_bfloat16 o[8];
    o[0] = f2bf(v0.x); o[1] = f2bf(v0.y); o[2] = f2bf(v0.z); o[3] = f2bf(v0.w);
    o[4] = f2bf(v1.x); o[5] = f2bf(v1.y); o[6] = f2bf(v1.z); o[7] = f2bf(v1.w);
    *(short8*)(tb + i) = *(short8*)o;
  } else {
    int idx = (bid - CONV_BLOCKS) * 256 + threadIdx.x;   // 0..65535
    int n = idx & 255, k = idx >> 8;
    float v = (k < 128) ? Wu[k * 256 + n] : Wm[(k - 128) * 256 + n];
    WcatT[n * 256 + k] = f2bf(v);
    W1T[n * 256 + k]   = f2bf(W1[k * 256 + n]);
    if (k < 128) WmT[n * 128 + k] = f2bf(Wm[k * 256 + n]);
    if (idx < 32768) {
      int k2 = idx >> 7, n2 = idx & 127;
      W2T[n2 * 256 + k2] = f2bf(W2[k2 * 128 + n2]);
    }
    if (idx < 256) bc[idx] = bu[idx] + bm[idx];
  }
}

// ---------------------------------------------------------------------------
// layer: one GEMM layer on a 64-row LDS tile with B persistent in VGPRs.
//   Ain (LDS): 64 rows x K0, XOR-swizzled (16B slot s holds chunk s^(r&7)).
//   Wt: global [NCOL][K0] bf16 (L2-hot; ~16 KB/wave loaded ONCE per layer).
// 8 waves split N: wave w owns JN*16 cols (JN = NCOL/128).
// 4 iters x 16 rows: KK ds_read_b128 + 2*KK*JN MFMA; epilogue -> LDS
// (swizzled, 256-col) or global fp32 (128-col).
// ---------------------------------------------------------------------------
template <int K0, int NCOL, bool RELU, bool TOGLB>
__device__ __forceinline__ void layer(
    const __hip_bfloat16* Ain,
    const __hip_bfloat16* __restrict__ Wt, const float* __restrict__ bias,
    __hip_bfloat16* Olds, float* __restrict__ Oglb,
    int wid, int quad, int lrow) {
  constexpr int KK = K0 / 32;
  constexpr int JN = NCOL / 128;
  const int c0 = wid * JN * 16;

  short8 bfr[JN][KK];
  float  bv[JN];
  #pragma unroll
  for (int j = 0; j < JN; ++j) {
    #pragma unroll
    for (int kc = 0; kc < KK; ++kc)
      bfr[j][kc] = *(const short8*)(Wt + (size_t)(c0 + j * 16 + lrow) * K0 +
                                    kc * 32 + quad * 8);
    bv[j] = bias[c0 + j * 16 + lrow];
  }

  #pragma unroll
  for (int it = 0; it < 4; ++it) {
    int r = it * 16 + lrow;
    short8 af[KK];
    #pragma unroll
    for (int kc = 0; kc < KK; ++kc)
      af[kc] = *(const short8*)&Ain[r * K0 + (((kc * 4 + quad) ^ (r & 7)) << 3)];
    floatx4 pa[JN], pb[JN];
    #pragma unroll
    for (int j = 0; j < JN; ++j) { pa[j] = {}; pb[j] = {}; }
    #pragma unroll
    for (int kc = 0; kc < KK; kc += 2)
      #pragma unroll
      for (int j = 0; j < JN; ++j) {
        pa[j] = mfma16(af[kc],     bfr[j][kc],     pa[j]);
        pb[j] = mfma16(af[kc + 1], bfr[j][kc + 1], pb[j]);
      }
    #pragma unroll
    for (int j = 0; j < JN; ++j) {
      floatx4 a = pa[j] + pb[j];
      int col = c0 + j * 16 + lrow;
      #pragma unroll
      for (int rr = 0; rr < 4; ++rr) {
        int row = it * 16 + quad * 4 + rr;
        float v = a[rr] + bv[j];
        if (RELU) v = fmaxf(v, 0.f);
        if (TOGLB) {
          Oglb[(size_t)row * NCOL + col] = v;
        } else {
          int ch = col >> 3;
          Olds[row * 256 + (((ch ^ (row & 7)) << 3) | (col & 7))] = f2bf(v);
        }
      }
    }
  }
}

// ---------------------------------------------------------------------------
// fused_mlp: one block = 64 rows of stream s (0 user / 1 pos / 2 neg),
// all 3 layers; B per layer in VGPRs, A/E/H in LDS; 3 barriers per block.
//
// R10 lesson: __launch_bounds__(512,2) only sets a MINIMUM waves/EU — the
// scheduler targeted 4 waves/SIMD, capped itself at 88 VGPRs, and sank the
// B-loads into the loop (MfmaUtil 10.7%). amdgpu_waves_per_eu(2,2) pins the
// occupancy target to exactly 2 waves/EU -> 256-VGPR budget -> the ~200-VGPR
// persistent-B working set stays resident.
//
// R11 (this round): gather_user is fused into the s==0 blocks. Each wave
// owns 8 rows: 50-neighbor bf16 gather (quad q handles nbr 4*it+q, lane
// slice lrow*16B), fp32 accumulate, cross-quad shfl reduce, mean -> bf16 ->
// swizzled LDS cols [128,256); users fp32 -> bf16 -> swizzled LDS cols
// [0,128). Removes the serialized gather_user dispatch and the 16.8 MB
// A_user HBM round-trip; the 210 MB L3 gather overlaps with s1/s2 MFMA work.
// ---------------------------------------------------------------------------
__global__ __launch_bounds__(512)
__attribute__((amdgpu_waves_per_eu(2, 2)))
void fused_mlp(
    const float* __restrict__ users,
    const __hip_bfloat16* __restrict__ tb,
    const int* __restrict__ pos_ids, const int* __restrict__ neg_ids,
    const int* __restrict__ nbr_ids,
    const __hip_bfloat16* __restrict__ WcatT,
    const __hip_bfloat16* __restrict__ WmT,
    const __hip_bfloat16* __restrict__ W1T,
    const __hip_bfloat16* __restrict__ W2T,
    const float* __restrict__ bc, const float* __restrict__ bmv,
    const float* __restrict__ b1, const float* __restrict__ b2,
    float* __restrict__ out) {
  __shared__ __hip_bfloat16 A_lds[64 * 256];   // 32 KB: A, then H
  __shared__ __hip_bfloat16 E_lds[64 * 256];   // 32 KB: E

  const int t    = threadIdx.x;
  const int lane = t & 63, wid = t >> 6;       // wid 0..7
  const int quad = lane >> 4, lrow = lane & 15;
  const int s    = blockIdx.x % 3;
  const long m0  = (long)(blockIdx.x / 3) * 64;

  // ---- stage A tile ----
  if (s == 0) {
    // in-block neighbor gather + user convert (was gather_user kernel).
    for (int rr = 0; rr < 8; ++rr) {
      const int r = (wid << 3) | rr;
      const size_t grow = (size_t)(m0 + r);
      const int* nb = nbr_ids + grow * NNBR;
      float acc[8] = {0.f, 0.f, 0.f, 0.f, 0.f, 0.f, 0.f, 0.f};
      #pragma unroll
      for (int it = 0; it < 13; ++it) {
        int j = (it << 2) + quad;
        if (j < NNBR) {
          int id = nb[j];
          short8 v = *(const short8*)(tb + (size_t)id * FEAT + (lrow << 3));
          #pragma unroll
          for (int e = 0; e < 8; ++e) acc[e] += bfb2f(v[e]);
        }
      }
      __hip_bfloat16 o[8];
      #pragma unroll
      for (int e = 0; e < 8; ++e) {
        float v = acc[e];
        v += __shfl_xor(v, 16, 64);
        v += __shfl_xor(v, 32, 64);
        o[e] = f2bf(v * (1.f / NNBR));
      }
      if (quad == 0) {
        int ch = 16 + lrow;                    // cols [128,256), one 16B chunk
        *(short8*)(A_lds + r * 256 + ((ch ^ (r & 7)) << 3)) = *(short8*)o;
      }
      // users fp32 -> bf16, cols [0,128): lane covers 2 consecutive cols
      float2 uv = ((const float2*)(users + grow * FEAT))[lane];
      __hip_bfloat162 t0; t0.x = f2bf(uv.x); t0.y = f2bf(uv.y);
      int col = lane << 1, ch2 = col >> 3;
      *(__hip_bfloat162*)(A_lds + r * 256 + ((ch2 ^ (r & 7)) << 3) + (col & 7)) = t0;
    }
  } else {
    const int* ids = (s == 1) ? pos_ids : neg_ids;
    #pragma unroll
    for (int i = 0; i < 2; ++i) {
      int c = t + i * 512;                     // 1024 slots: r=c>>4, sl=c&15
      int r = c >> 4, sl = c & 15;
      int id = ids[m0 + r];
      gld16(tb + ((size_t)id << 7) + ((sl ^ (r & 7)) << 3),
            A_lds + (c << 3));
    }
  }
  __syncthreads();                             // A staged (vmcnt(0) drain / LDS writes)

  // ---- layer 0 -> E_lds (no relu) ----
  if (s == 0)
    layer<256, 256, false, false>(A_lds, WcatT, bc, E_lds, nullptr,
                                  wid, quad, lrow);
  else
    layer<128, 256, false, false>(A_lds, WmT, bmv, E_lds, nullptr,
                                  wid, quad, lrow);
  __syncthreads();                             // E complete (A reads done)

  // ---- layer 1: H = relu(E @ W1^T + b1) -> A_lds ----
  layer<256, 256, true, false>(E_lds, W1T, b1, A_lds, nullptr,
                               wid, quad, lrow);
  __syncthreads();                             // H complete

  // ---- layer 2: out = relu(H @ W2^T + b2) -> global fp32 ----
  layer<256, 128, true, true>(A_lds, W2T, b2, nullptr,
                              out + ((size_t)s * BATCH_N + m0) * 128,
                              wid, quad, lrow);
}

// ---------------------------------------------------------------------------
extern "C" void kernel_launch(void* const* d_in, const int* in_sizes, int n_in,
                              void* d_out, int out_size, void* d_ws, size_t ws_size,
                              hipStream_t stream) {
  const float* users   = (const float*)d_in[0];
  // d_in[1] pos_movies, d_in[2] neg_movies, d_in[3] user_ids: unused by ref
  const int*   pos_ids = (const int*)d_in[4];
  const int*   neg_ids = (const int*)d_in[5];
  const int*   nbr_ids = (const int*)d_in[6];
  const float* table   = (const float*)d_in[7];
  const float* Wu = (const float*)d_in[8];
  const float* bu = (const float*)d_in[9];
  const float* Wm = (const float*)d_in[10];
  const float* bm = (const float*)d_in[11];
  const float* W1 = (const float*)d_in[12];
  const float* b1 = (const float*)d_in[13];
  const float* W2 = (const float*)d_in[14];
  const float* b2 = (const float*)d_in[15];
  float* out = (float*)d_out;

  // workspace carve (all 256B aligned). Total ~26 MB.
  char* p = (char*)d_ws;
  auto carve = [&](size_t bytes) { char* r = p; p += (bytes + 255) & ~(size_t)255; return r; };
  __hip_bfloat16* tb     = (__hip_bfloat16*)carve((size_t)NUM_MOVIES_N * FEAT * 2);
  __hip_bfloat16* WcatT  = (__hip_bfloat16*)carve(256 * 256 * 2);
  __hip_bfloat16* WmT    = (__hip_bfloat16*)carve(256 * 128 * 2);
  __hip_bfloat16* W1T    = (__hip_bfloat16*)carve(256 * 256 * 2);
  __hip_bfloat16* W2T    = (__hip_bfloat16*)carve(128 * 256 * 2);
  float*          bc     = (float*)carve(256 * 4);

  prep_all<<<CONV_BLOCKS + 256, 256, 0, stream>>>(
      table, tb, Wu, Wm, W1, W2, bu, bm, WcatT, WmT, W1T, W2T, bc);
  fused_mlp<<<3 * BATCH_N / 64, 512, 0, stream>>>(
      users, tb, pos_ids, neg_ids, nbr_ids, WcatT, WmT, W1T, W2T,
      bc, bm, b1, b2, out);
}